// Round 3
// baseline (1733.643 us; speedup 1.0000x reference)
//
#include <hip/hip_runtime.h>
#include <stdint.h>

// ---------------------------------------------------------------------------
// DialogueTransformer: B=8,S=2048,D=1024,H=8,HD=128  -> 16384 tokens
// Reference math is fp32; attention is per-token 8x8 head mixing.
// Round 2 theory: harness tensors are FP32 (reference dtype), not bf16 —
// rounds 0/1 read fp32 bits as bf16 (mantissa halves hit NaN patterns).
// Internal compute: bf16 MFMA (16x16x32) with fp32 accumulation; fp32->bf16
// conversion inline during GEMM staging. Activations stored bf16.
// Memory: d_ws = 2 x 32MB bf16 buffers (64MB). d_out (64MB fp32) doubles as
// two 32MB bf16 scratch halves; final GEMM overwrites all of d_out in fp32.
// ---------------------------------------------------------------------------

#define TOKENS 16384
#define DMODEL 1024

typedef unsigned short ushort_t;
typedef __attribute__((ext_vector_type(8))) short short8;
typedef __attribute__((ext_vector_type(4))) float floatx4;

__device__ __forceinline__ float b2f(ushort_t u) {
  union { uint32_t i; float f; } v; v.i = ((uint32_t)u) << 16; return v.f;
}
__device__ __forceinline__ ushort_t f2b(float f) {
  union { float f; uint32_t i; } v; v.f = f;
  uint32_t r = v.i + 0x7fffu + ((v.i >> 16) & 1u);
  return (ushort_t)(r >> 16);
}

// load 8 fp32 from g (16B-aligned), round to bf16, store 16B to LDS/dst
__device__ __forceinline__ void pack8(const float* __restrict__ g, ushort_t* dst) {
  float4 x = *(const float4*)g;
  float4 y = *(const float4*)(g + 4);
  ushort_t o[8] = {f2b(x.x), f2b(x.y), f2b(x.z), f2b(x.w),
                   f2b(y.x), f2b(y.y), f2b(y.z), f2b(y.w)};
  *(uint4*)dst = *(uint4*)o;
}

// ---------------------------------------------------------------------------
// x = input + pe (fp32 in, bf16 out), 8 elems/thread
// ---------------------------------------------------------------------------
__global__ __launch_bounds__(256) void add_pe_kernel(
    const float* __restrict__ in, const float* __restrict__ pe,
    ushort_t* __restrict__ out) {
  int idx = (blockIdx.x * 256 + threadIdx.x) * 8;
  int d = idx & (DMODEL - 1);
  float4 a0 = *(const float4*)(in + idx);
  float4 a1 = *(const float4*)(in + idx + 4);
  float4 p0 = *(const float4*)(pe + d);
  float4 p1 = *(const float4*)(pe + d + 4);
  ushort_t o[8] = {f2b(a0.x + p0.x), f2b(a0.y + p0.y), f2b(a0.z + p0.z), f2b(a0.w + p0.w),
                   f2b(a1.x + p1.x), f2b(a1.y + p1.y), f2b(a1.z + p1.z), f2b(a1.w + p1.w)};
  *(uint4*)(out + idx) = *(uint4*)o;
}

// ---------------------------------------------------------------------------
// C[t,n] = sum_k A[t,k] * W[n,k] + bias[n]
// M=16384, N=K=1024. 128x128 tile, 4 waves x (64x64), MFMA 16x16x32 bf16.
// A: bf16 (or fp32 if flags&2). W,bias: fp32 (converted inline). Out: bf16
// (or fp32 if flags&4). flags&1 = relu.
// ---------------------------------------------------------------------------
#define GF_RELU 1
#define GF_A32 2
#define GF_OUT32 4

__global__ __launch_bounds__(256) void gemm_bt_kernel(
    const void* __restrict__ Ap, const float* __restrict__ W,
    const float* __restrict__ bias, void* __restrict__ Cp, int flags) {
  constexpr int K = 1024, N = 1024, BK = 32;
  __shared__ __align__(16) ushort_t sA[128 * BK];
  __shared__ __align__(16) ushort_t sB[128 * BK];

  const int t = threadIdx.x;
  const int lane = t & 63;
  const int m0 = blockIdx.x * 128;
  const int n0 = blockIdx.y * 128;
  const int wm = ((t >> 6) >> 1) * 64;
  const int wn = ((t >> 6) & 1) * 64;

  floatx4 acc[4][4] = {};

  const int row = t >> 2;       // 0..63
  const int kc = (t & 3) * 8;   // 0,8,16,24
  const bool a32 = (flags & GF_A32) != 0;
  const ushort_t* gA16 = (const ushort_t*)Ap + (size_t)(m0 + row) * K + kc;
  const float* gA32 = (const float*)Ap + (size_t)(m0 + row) * K + kc;
  const float* gB = W + (size_t)(n0 + row) * K + kc;
  const int lo = t * 8;  // == row*BK + kc

  for (int k0 = 0; k0 < K; k0 += BK) {
    if (a32) {
      pack8(gA32 + k0, sA + lo);
      pack8(gA32 + k0 + (size_t)64 * K, sA + lo + 2048);
    } else {
      uint4 a0 = *(const uint4*)(gA16 + k0);
      uint4 a1 = *(const uint4*)(gA16 + k0 + (size_t)64 * K);
      *(uint4*)(sA + lo) = a0;
      *(uint4*)(sA + lo + 2048) = a1;
    }
    pack8(gB + k0, sB + lo);
    pack8(gB + k0 + (size_t)64 * K, sB + lo + 2048);
    __syncthreads();

    short8 af[4], bf[4];
#pragma unroll
    for (int i = 0; i < 4; i++) {
      af[i] = *(const short8*)&sA[(wm + i * 16 + (lane & 15)) * BK + (lane >> 4) * 8];
      bf[i] = *(const short8*)&sB[(wn + i * 16 + (lane & 15)) * BK + (lane >> 4) * 8];
    }
#pragma unroll
    for (int i = 0; i < 4; i++)
#pragma unroll
      for (int j = 0; j < 4; j++)
        acc[i][j] = __builtin_amdgcn_mfma_f32_16x16x32_bf16(af[i], bf[j], acc[i][j], 0, 0, 0);
    __syncthreads();
  }

  // epilogue: C/D layout col=lane&15, row=(lane>>4)*4+reg  [m89-verified]
  const int rbase = (lane >> 4) * 4;
  const bool relu = (flags & GF_RELU) != 0;
  const bool o32 = (flags & GF_OUT32) != 0;
#pragma unroll
  for (int j = 0; j < 4; j++) {
    const int col = n0 + wn + j * 16 + (lane & 15);
    const float bv = bias[col];
#pragma unroll
    for (int i = 0; i < 4; i++) {
#pragma unroll
      for (int r = 0; r < 4; r++) {
        const int rowg = m0 + wm + i * 16 + rbase + r;
        float v = acc[i][j][r] + bv;
        if (relu) v = fmaxf(v, 0.0f);
        if (o32) ((float*)Cp)[(size_t)rowg * N + col] = v;
        else ((ushort_t*)Cp)[(size_t)rowg * N + col] = f2b(v);
      }
    }
  }
}

// ---------------------------------------------------------------------------
// Per-token head-mix attention (bf16 buffers). One wave/token, 4 tokens/block.
// O may alias Q: all reads staged to LDS before any global write.
// ---------------------------------------------------------------------------
__global__ __launch_bounds__(256) void attn_kernel(
    const ushort_t* Q, const ushort_t* Kp, const ushort_t* Vp, ushort_t* O) {
  __shared__ __align__(16) ushort_t sq[4][1024];
  __shared__ __align__(16) ushort_t sk[4][1024];
  __shared__ __align__(16) ushort_t sv[4][1024];
  __shared__ float sp[4][64];

  const int t = threadIdx.x;
  const int w = t >> 6;
  const int lane = t & 63;
  const size_t base = ((size_t)blockIdx.x * 4 + w) * 1024;

  ((uint4*)sq[w])[lane] = ((const uint4*)(Q + base))[lane];
  ((uint4*)sq[w])[lane + 64] = ((const uint4*)(Q + base))[lane + 64];
  ((uint4*)sk[w])[lane] = ((const uint4*)(Kp + base))[lane];
  ((uint4*)sk[w])[lane + 64] = ((const uint4*)(Kp + base))[lane + 64];
  ((uint4*)sv[w])[lane] = ((const uint4*)(Vp + base))[lane];
  ((uint4*)sv[w])[lane + 64] = ((const uint4*)(Vp + base))[lane + 64];
  __syncthreads();

  {  // scores + softmax: lane = i*8 + j
    const int i = lane >> 3, j = lane & 7;
    const ushort_t* qr = &sq[w][i * 128];
    const ushort_t* kr = &sk[w][j * 128];
    float s = 0.0f;
#pragma unroll 16
    for (int h = 0; h < 128; h++) s += b2f(qr[h]) * b2f(kr[h]);
    s *= 0.08838834764831845f;  // 1/sqrt(128)
    float m = s;
#pragma unroll
    for (int off = 1; off < 8; off <<= 1) m = fmaxf(m, __shfl_xor(m, off, 64));
    float e = __expf(s - m);
    float sum = e;
#pragma unroll
    for (int off = 1; off < 8; off <<= 1) sum += __shfl_xor(sum, off, 64);
    sp[w][lane] = e / sum;
  }
  __syncthreads();

  {  // out[i][h] = sum_j P[i][j] * v[j][h]; lane: row i=lane>>3, hb=(lane&7)*16
    const int i = lane >> 3;
    const int hb = (lane & 7) * 16;
    float p[8];
#pragma unroll
    for (int jj = 0; jj < 8; jj++) p[jj] = sp[w][i * 8 + jj];
    float o[16];
#pragma unroll
    for (int h = 0; h < 16; h++) {
      float acc = 0.0f;
#pragma unroll
      for (int jj = 0; jj < 8; jj++) acc += p[jj] * b2f(sv[w][jj * 128 + hb + h]);
      o[h] = acc;
    }
    uint32_t packed[8];
#pragma unroll
    for (int u = 0; u < 8; u++)
      packed[u] = (uint32_t)f2b(o[2 * u]) | ((uint32_t)f2b(o[2 * u + 1]) << 16);
    uint4* dst = (uint4*)(O + base + i * 128 + hb);
    dst[0] = *(uint4*)&packed[0];
    dst[1] = *(uint4*)&packed[4];
  }
}

// ---------------------------------------------------------------------------
extern "C" void kernel_launch(void* const* d_in, const int* in_sizes, int n_in,
                              void* d_out, int out_size, void* d_ws, size_t ws_size,
                              hipStream_t stream) {
  const float* input_seq = (const float*)d_in[0];
  const float* output_seq = (const float*)d_in[1];
  const float* pe = (const float*)d_in[2];
  const float* enc_wq = (const float*)d_in[3];  const float* enc_bq = (const float*)d_in[4];
  const float* enc_wk = (const float*)d_in[5];  const float* enc_bk = (const float*)d_in[6];
  const float* enc_wv = (const float*)d_in[7];  const float* enc_bv = (const float*)d_in[8];
  const float* enc_w1 = (const float*)d_in[9];  const float* enc_b1 = (const float*)d_in[10];
  const float* enc_w2 = (const float*)d_in[11]; const float* enc_b2 = (const float*)d_in[12];
  const float* dsq_w = (const float*)d_in[13];  const float* dsq_b = (const float*)d_in[14];
  const float* dsk_w = (const float*)d_in[15];  const float* dsk_b = (const float*)d_in[16];
  const float* dsv_w = (const float*)d_in[17];  const float* dsv_b = (const float*)d_in[18];
  const float* dcq_w = (const float*)d_in[19];  const float* dcq_b = (const float*)d_in[20];
  const float* dck_w = (const float*)d_in[21];  const float* dck_b = (const float*)d_in[22];
  const float* dcv_w = (const float*)d_in[23];  const float* dcv_b = (const float*)d_in[24];
  const float* dec_w1 = (const float*)d_in[25]; const float* dec_b1 = (const float*)d_in[26];
  const float* dec_w2 = (const float*)d_in[27]; const float* dec_b2 = (const float*)d_in[28];
  const float* fc_w = (const float*)d_in[29];   const float* fc_b = (const float*)d_in[30];

  const size_t SZ = (size_t)TOKENS * DMODEL;  // 16.7M elems
  ushort_t* bA = (ushort_t*)d_ws;        // 32MB bf16
  ushort_t* bB = bA + SZ;                // 32MB bf16
  ushort_t* oL = (ushort_t*)d_out;       // d_out lower 32MB as bf16 scratch
  ushort_t* oH = oL + SZ;                // d_out upper 32MB as bf16 scratch
  float* outf = (float*)d_out;           // final fp32 output (all 64MB)

  const dim3 gG(TOKENS / 128, DMODEL / 128);  // (128, 8)
  const dim3 blk(256);
  const int gPE = TOKENS * DMODEL / (256 * 8);  // 8192
  const int gAT = TOKENS / 4;                   // 4096

  add_pe_kernel<<<gPE, blk, 0, stream>>>(input_seq, pe, bA);                 // bA = x
  // encoder self-attn
  gemm_bt_kernel<<<gG, blk, 0, stream>>>(bA, enc_wq, enc_bq, bB, 0);         // bB = q
  gemm_bt_kernel<<<gG, blk, 0, stream>>>(bA, enc_wk, enc_bk, oL, 0);         // oL = k
  gemm_bt_kernel<<<gG, blk, 0, stream>>>(bA, enc_wv, enc_bv, oH, 0);         // oH = v
  attn_kernel<<<gAT, blk, 0, stream>>>(bB, oL, oH, bB);                      // bB = a
  // encoder FFN
  gemm_bt_kernel<<<gG, blk, 0, stream>>>(bB, enc_w1, enc_b1, bA, GF_RELU);   // bA = h1
  gemm_bt_kernel<<<gG, blk, 0, stream>>>(bA, enc_w2, enc_b2, bB, 0);         // bB = enc_out
  // decoder self-attn (A = output_seq, fp32)
  gemm_bt_kernel<<<gG, blk, 0, stream>>>(output_seq, dsq_w, dsq_b, bA, GF_A32);  // bA = q2
  gemm_bt_kernel<<<gG, blk, 0, stream>>>(output_seq, dsk_w, dsk_b, oL, GF_A32);  // oL = k2
  gemm_bt_kernel<<<gG, blk, 0, stream>>>(output_seq, dsv_w, dsv_b, oH, GF_A32);  // oH = v2
  attn_kernel<<<gAT, blk, 0, stream>>>(bA, oL, oH, bA);                      // bA = sa
  // decoder cross-attn (q from sa, k/v from enc_out)
  gemm_bt_kernel<<<gG, blk, 0, stream>>>(bA, dcq_w, dcq_b, oL, 0);           // oL = q3
  gemm_bt_kernel<<<gG, blk, 0, stream>>>(bB, dck_w, dck_b, oH, 0);           // oH = k3
  gemm_bt_kernel<<<gG, blk, 0, stream>>>(bB, dcv_w, dcv_b, bA, 0);           // bA = v3
  attn_kernel<<<gAT, blk, 0, stream>>>(oL, oH, bA, oL);                      // oL = ca
  // decoder FFN + final fc
  gemm_bt_kernel<<<gG, blk, 0, stream>>>(oL, dec_w1, dec_b1, bB, GF_RELU);   // bB = h2
  gemm_bt_kernel<<<gG, blk, 0, stream>>>(bB, dec_w2, dec_b2, bA, 0);         // bA = dec_out
  gemm_bt_kernel<<<gG, blk, 0, stream>>>(bA, fc_w, fc_b, outf, GF_OUT32);    // d_out fp32
}

// Round 4
// 1188.936 us; speedup vs baseline: 1.4581x; 1.4581x over previous
//
#include <hip/hip_runtime.h>
#include <stdint.h>

// ---------------------------------------------------------------------------
// DialogueTransformer: B=8,S=2048,D=1024,H=8,HD=128 -> 16384 tokens, fp32 I/O.
// Attention = per-token 8x8 head mixing. 14x [16384x1024]@[1024x1024]^T GEMMs.
// Round 4: pre-convert weights to bf16 (once), m97-structure GEMM
// (global_load_lds width=16), coalesced LDS-transpose epilogue.
// ws layout: bA(32MB) | bB(32MB) | wts_bf16(28MB)  = 92MB.
// d_out (64MB) doubles as two 32MB bf16 scratch halves until the final GEMM.
// ---------------------------------------------------------------------------

#define TOKENS 16384
#define DMODEL 1024

typedef unsigned short ushort_t;
typedef __attribute__((ext_vector_type(8))) short short8;
typedef __attribute__((ext_vector_type(4))) float floatx4;

__device__ __forceinline__ float b2f(ushort_t u) {
  union { uint32_t i; float f; } v; v.i = ((uint32_t)u) << 16; return v.f;
}
__device__ __forceinline__ ushort_t f2b(float f) {
  union { float f; uint32_t i; } v; v.f = f;
  uint32_t r = v.i + 0x7fffu + ((v.i >> 16) & 1u);
  return (ushort_t)(r >> 16);
}

// load 8 fp32 (16B-aligned), round to bf16, store 16B
__device__ __forceinline__ void pack8(const float* __restrict__ g, ushort_t* dst) {
  float4 x = *(const float4*)g;
  float4 y = *(const float4*)(g + 4);
  ushort_t o[8] = {f2b(x.x), f2b(x.y), f2b(x.z), f2b(x.w),
                   f2b(y.x), f2b(y.y), f2b(y.z), f2b(y.w)};
  *(uint4*)dst = *(uint4*)o;
}

// async global->LDS, 16B per lane (wave-uniform base + lane*16)
#define GLD16(g, l)                                                          \
  __builtin_amdgcn_global_load_lds(                                          \
      (const __attribute__((address_space(1))) void*)(g),                    \
      (__attribute__((address_space(3))) void*)(l), 16, 0, 0)

// ---------------------------------------------------------------------------
// weight pre-conversion: 14 matrices of 1024x1024 fp32 -> bf16
// ---------------------------------------------------------------------------
struct ConvArgs {
  const float* src[14];
  ushort_t* dst[14];
};

__global__ __launch_bounds__(256) void conv_w_kernel(ConvArgs a) {
  const int w = blockIdx.y;
  const int idx = (blockIdx.x * 256 + threadIdx.x) * 8;
  pack8(a.src[w] + idx, a.dst[w] + idx);
}

// ---------------------------------------------------------------------------
// x = input + pe (fp32 in, bf16 out)
// ---------------------------------------------------------------------------
__global__ __launch_bounds__(256) void add_pe_kernel(
    const float* __restrict__ in, const float* __restrict__ pe,
    ushort_t* __restrict__ out) {
  int idx = (blockIdx.x * 256 + threadIdx.x) * 8;
  int d = idx & (DMODEL - 1);
  float4 a0 = *(const float4*)(in + idx);
  float4 a1 = *(const float4*)(in + idx + 4);
  float4 p0 = *(const float4*)(pe + d);
  float4 p1 = *(const float4*)(pe + d + 4);
  ushort_t o[8] = {f2b(a0.x + p0.x), f2b(a0.y + p0.y), f2b(a0.z + p0.z), f2b(a0.w + p0.w),
                   f2b(a1.x + p1.x), f2b(a1.y + p1.y), f2b(a1.z + p1.z), f2b(a1.w + p1.w)};
  *(uint4*)(out + idx) = *(uint4*)o;
}

// ---------------------------------------------------------------------------
// C[t,n] = sum_k A[t,k]*W[n,k] + bias[n].  M=16384, N=K=1024.
// 128x128 tile, 4 waves x (64x64), MFMA 16x16x32 bf16, BK=32.
// A: bf16 (GLD16) or fp32 if flags&GF_A32 (pack8). W: bf16 (GLD16).
// Out: bf16 via LDS-transpose coalesced stores, or fp32 scattered (GF_OUT32).
// ---------------------------------------------------------------------------
#define GF_RELU 1
#define GF_A32 2
#define GF_OUT32 4

__global__ __launch_bounds__(256) void gemm_bt_kernel(
    const void* __restrict__ Ap, const ushort_t* __restrict__ W,
    const float* __restrict__ bias, void* __restrict__ Cp, int flags) {
  constexpr int K = 1024, N = 1024, BK = 32;
  // sA/sB (8KB each) alias the epilogue buffer sC (128x136 bf16 = 34816B)
  __shared__ __align__(16) ushort_t smem[128 * 136];
  ushort_t* sA = smem;
  ushort_t* sB = smem + 128 * BK;

  const int t = threadIdx.x;
  const int lane = t & 63;
  const int m0 = blockIdx.x * 128;
  const int n0 = blockIdx.y * 128;
  const int wm = ((t >> 6) >> 1) * 64;
  const int wn = ((t >> 6) & 1) * 64;

  floatx4 acc[4][4] = {};

  const int row = t >> 2;       // 0..63
  const int kc = (t & 3) * 8;   // 0,8,16,24
  const bool a32 = (flags & GF_A32) != 0;
  const ushort_t* gA16 = (const ushort_t*)Ap + (size_t)(m0 + row) * K + kc;
  const float* gA32 = (const float*)Ap + (size_t)(m0 + row) * K + kc;
  const ushort_t* gW = W + (size_t)(n0 + row) * K + kc;
  const int lo = t * 8;  // == row*BK + kc

  for (int k0 = 0; k0 < K; k0 += BK) {
    if (a32) {
      pack8(gA32 + k0, sA + lo);
      pack8(gA32 + k0 + (size_t)64 * K, sA + lo + 2048);
    } else {
      GLD16(gA16 + k0, sA + lo);
      GLD16(gA16 + k0 + (size_t)64 * K, sA + lo + 2048);
    }
    GLD16(gW + k0, sB + lo);
    GLD16(gW + k0 + (size_t)64 * K, sB + lo + 2048);
    __syncthreads();

    short8 af[4], bf[4];
#pragma unroll
    for (int i = 0; i < 4; i++) {
      af[i] = *(const short8*)&sA[(wm + i * 16 + (lane & 15)) * BK + (lane >> 4) * 8];
      bf[i] = *(const short8*)&sB[(wn + i * 16 + (lane & 15)) * BK + (lane >> 4) * 8];
    }
#pragma unroll
    for (int i = 0; i < 4; i++)
#pragma unroll
      for (int j = 0; j < 4; j++)
        acc[i][j] = __builtin_amdgcn_mfma_f32_16x16x32_bf16(af[i], bf[j], acc[i][j], 0, 0, 0);
    __syncthreads();
  }

  // ---- epilogue. C/D layout: col=lane&15, row=(lane>>4)*4+reg [m89] ----
  const int rbase = (lane >> 4) * 4;
  const bool relu = (flags & GF_RELU) != 0;

  if (flags & GF_OUT32) {  // final GEMM: fp32 scattered stores (1 of 14)
#pragma unroll
    for (int j = 0; j < 4; j++) {
      const int col = n0 + wn + j * 16 + (lane & 15);
      const float bv = bias[col];
#pragma unroll
      for (int i = 0; i < 4; i++)
#pragma unroll
        for (int r = 0; r < 4; r++) {
          const int rowg = m0 + wm + i * 16 + rbase + r;
          float v = acc[i][j][r] + bv;
          if (relu) v = fmaxf(v, 0.0f);
          ((float*)Cp)[(size_t)rowg * N + col] = v;
        }
    }
    return;
  }

  // bf16 path: acc -> sC (padded 136) -> coalesced row-major uint4 stores
  ushort_t* sC = smem;
#pragma unroll
  for (int j = 0; j < 4; j++) {
    const int cl = wn + j * 16 + (lane & 15);
    const float bv = bias[n0 + cl];
#pragma unroll
    for (int i = 0; i < 4; i++) {
      const int rl = wm + i * 16 + rbase;
#pragma unroll
      for (int r = 0; r < 4; r++) {
        float v = acc[i][j][r] + bv;
        if (relu) v = fmaxf(v, 0.0f);
        sC[(rl + r) * 136 + cl] = f2b(v);
      }
    }
  }
  __syncthreads();
#pragma unroll
  for (int p = 0; p < 8; p++) {
    const int rl = p * 16 + (t >> 4);
    const int cl = (t & 15) * 8;
    uint4 v = *(const uint4*)&sC[rl * 136 + cl];
    *(uint4*)((ushort_t*)Cp + (size_t)(m0 + rl) * N + n0 + cl) = v;
  }
}

// ---------------------------------------------------------------------------
// Per-token head-mix attention (bf16). One wave/token, 4 tokens/block.
// O may alias Q: all reads staged to LDS before any global write.
// ---------------------------------------------------------------------------
__global__ __launch_bounds__(256) void attn_kernel(
    const ushort_t* Q, const ushort_t* Kp, const ushort_t* Vp, ushort_t* O) {
  __shared__ __align__(16) ushort_t sq[4][1024];
  __shared__ __align__(16) ushort_t sk[4][1024];
  __shared__ __align__(16) ushort_t sv[4][1024];
  __shared__ float sp[4][64];

  const int t = threadIdx.x;
  const int w = t >> 6;
  const int lane = t & 63;
  const size_t base = ((size_t)blockIdx.x * 4 + w) * 1024;

  ((uint4*)sq[w])[lane] = ((const uint4*)(Q + base))[lane];
  ((uint4*)sq[w])[lane + 64] = ((const uint4*)(Q + base))[lane + 64];
  ((uint4*)sk[w])[lane] = ((const uint4*)(Kp + base))[lane];
  ((uint4*)sk[w])[lane + 64] = ((const uint4*)(Kp + base))[lane + 64];
  ((uint4*)sv[w])[lane] = ((const uint4*)(Vp + base))[lane];
  ((uint4*)sv[w])[lane + 64] = ((const uint4*)(Vp + base))[lane + 64];
  __syncthreads();

  {  // scores + softmax: lane = i*8 + j
    const int i = lane >> 3, j = lane & 7;
    const ushort_t* qr = &sq[w][i * 128];
    const ushort_t* kr = &sk[w][j * 128];
    float s = 0.0f;
#pragma unroll 16
    for (int h = 0; h < 128; h++) s += b2f(qr[h]) * b2f(kr[h]);
    s *= 0.08838834764831845f;  // 1/sqrt(128)
    float m = s;
#pragma unroll
    for (int off = 1; off < 8; off <<= 1) m = fmaxf(m, __shfl_xor(m, off, 64));
    float e = __expf(s - m);
    float sum = e;
#pragma unroll
    for (int off = 1; off < 8; off <<= 1) sum += __shfl_xor(sum, off, 64);
    sp[w][lane] = e / sum;
  }
  __syncthreads();

  {  // out[i][h] = sum_j P[i][j]*v[j][h]
    const int i = lane >> 3;
    const int hb = (lane & 7) * 16;
    float p[8];
#pragma unroll
    for (int jj = 0; jj < 8; jj++) p[jj] = sp[w][i * 8 + jj];
    float o[16];
#pragma unroll
    for (int h = 0; h < 16; h++) {
      float acc = 0.0f;
#pragma unroll
      for (int jj = 0; jj < 8; jj++) acc += p[jj] * b2f(sv[w][jj * 128 + hb + h]);
      o[h] = acc;
    }
    uint32_t packed[8];
#pragma unroll
    for (int u = 0; u < 8; u++)
      packed[u] = (uint32_t)f2b(o[2 * u]) | ((uint32_t)f2b(o[2 * u + 1]) << 16);
    uint4* dst = (uint4*)(O + base + i * 128 + hb);
    dst[0] = *(uint4*)&packed[0];
    dst[1] = *(uint4*)&packed[4];
  }
}

// ---------------------------------------------------------------------------
extern "C" void kernel_launch(void* const* d_in, const int* in_sizes, int n_in,
                              void* d_out, int out_size, void* d_ws, size_t ws_size,
                              hipStream_t stream) {
  const float* input_seq = (const float*)d_in[0];
  const float* output_seq = (const float*)d_in[1];
  const float* pe = (const float*)d_in[2];
  const float* wsrc[14] = {
      (const float*)d_in[3],  (const float*)d_in[5],  (const float*)d_in[7],
      (const float*)d_in[9],  (const float*)d_in[11], (const float*)d_in[13],
      (const float*)d_in[15], (const float*)d_in[17], (const float*)d_in[19],
      (const float*)d_in[21], (const float*)d_in[23], (const float*)d_in[25],
      (const float*)d_in[27], (const float*)d_in[29]};
  const float* enc_bq = (const float*)d_in[4];
  const float* enc_bk = (const float*)d_in[6];
  const float* enc_bv = (const float*)d_in[8];
  const float* enc_b1 = (const float*)d_in[10];
  const float* enc_b2 = (const float*)d_in[12];
  const float* dsq_b = (const float*)d_in[14];
  const float* dsk_b = (const float*)d_in[16];
  const float* dsv_b = (const float*)d_in[18];
  const float* dcq_b = (const float*)d_in[20];
  const float* dck_b = (const float*)d_in[22];
  const float* dcv_b = (const float*)d_in[24];
  const float* dec_b1 = (const float*)d_in[26];
  const float* dec_b2 = (const float*)d_in[28];
  const float* fc_b = (const float*)d_in[30];

  const size_t SZ = (size_t)TOKENS * DMODEL;   // 16.7M elems
  const size_t WSZ = (size_t)DMODEL * DMODEL;  // 1M elems
  ushort_t* bA = (ushort_t*)d_ws;        // 32MB
  ushort_t* bB = bA + SZ;                // 32MB
  ushort_t* wts = bB + SZ;               // 28MB bf16 weights
  ushort_t* oL = (ushort_t*)d_out;       // d_out lower 32MB as bf16 scratch
  ushort_t* oH = oL + SZ;                // d_out upper 32MB as bf16 scratch
  float* outf = (float*)d_out;

  // weight idx: 0 ewq,1 ewk,2 ewv,3 ew1,4 ew2,5 dsq,6 dsk,7 dsv,8 dcq,9 dck,
  //             10 dcv,11 dw1,12 dw2,13 fc
  ConvArgs ca;
#pragma unroll
  for (int i = 0; i < 14; i++) { ca.src[i] = wsrc[i]; ca.dst[i] = wts + (size_t)i * WSZ; }

  const dim3 gG(TOKENS / 128, DMODEL / 128);  // (128, 8)
  const dim3 blk(256);
  const int gPE = TOKENS * DMODEL / (256 * 8);  // 8192
  const int gAT = TOKENS / 4;                   // 4096

  conv_w_kernel<<<dim3(WSZ / (256 * 8), 14), blk, 0, stream>>>(ca);
  add_pe_kernel<<<gPE, blk, 0, stream>>>(input_seq, pe, bA);                   // bA = x
  // encoder self-attn
  gemm_bt_kernel<<<gG, blk, 0, stream>>>(bA, wts + 0 * WSZ, enc_bq, bB, 0);    // bB = q
  gemm_bt_kernel<<<gG, blk, 0, stream>>>(bA, wts + 1 * WSZ, enc_bk, oL, 0);    // oL = k
  gemm_bt_kernel<<<gG, blk, 0, stream>>>(bA, wts + 2 * WSZ, enc_bv, oH, 0);    // oH = v
  attn_kernel<<<gAT, blk, 0, stream>>>(bB, oL, oH, bB);                        // bB = a
  // encoder FFN
  gemm_bt_kernel<<<gG, blk, 0, stream>>>(bB, wts + 3 * WSZ, enc_b1, bA, GF_RELU);  // bA = h1
  gemm_bt_kernel<<<gG, blk, 0, stream>>>(bA, wts + 4 * WSZ, enc_b2, bB, 0);    // bB = enc_out
  // decoder self-attn (A = output_seq fp32)
  gemm_bt_kernel<<<gG, blk, 0, stream>>>(output_seq, wts + 5 * WSZ, dsq_b, bA, GF_A32);  // bA = q2
  gemm_bt_kernel<<<gG, blk, 0, stream>>>(output_seq, wts + 6 * WSZ, dsk_b, oL, GF_A32);  // oL = k2
  gemm_bt_kernel<<<gG, blk, 0, stream>>>(output_seq, wts + 7 * WSZ, dsv_b, oH, GF_A32);  // oH = v2
  attn_kernel<<<gAT, blk, 0, stream>>>(bA, oL, oH, bA);                        // bA = sa
  // decoder cross-attn (q from sa, k/v from enc_out)
  gemm_bt_kernel<<<gG, blk, 0, stream>>>(bA, wts + 8 * WSZ, dcq_b, oL, 0);     // oL = q3
  gemm_bt_kernel<<<gG, blk, 0, stream>>>(bB, wts + 9 * WSZ, dck_b, oH, 0);     // oH = k3
  gemm_bt_kernel<<<gG, blk, 0, stream>>>(bB, wts + 10 * WSZ, dcv_b, bA, 0);    // bA = v3
  attn_kernel<<<gAT, blk, 0, stream>>>(oL, oH, bA, oL);                        // oL = ca
  // decoder FFN + final fc
  gemm_bt_kernel<<<gG, blk, 0, stream>>>(oL, wts + 11 * WSZ, dec_b1, bB, GF_RELU); // bB = h2
  gemm_bt_kernel<<<gG, blk, 0, stream>>>(bB, wts + 12 * WSZ, dec_b2, bA, 0);   // bA = dec_out
  gemm_bt_kernel<<<gG, blk, 0, stream>>>(bA, wts + 13 * WSZ, fc_b, outf, GF_OUT32); // d_out
}

// Round 5
// 994.162 us; speedup vs baseline: 1.7438x; 1.1959x over previous
//
#include <hip/hip_runtime.h>
#include <stdint.h>

// ---------------------------------------------------------------------------
// DialogueTransformer: B=8,S=2048,D=1024,H=8,HD=128 -> 16384 tokens, fp32 I/O.
// Attention = per-token 8x8 head mixing. 14x [16384x1024]@[1024x1024]^T GEMMs.
// Round 5: branch-free templated GEMM K-loop, BK=64 (16 iters, half the
// barrier drains), XOR-swizzled LDS (conflict-free ds_read_b128 with GLD16),
// output_seq pre-converted to bf16 (no fp32 path in any GEMM K-loop).
// ws layout: bA(32MB) | bB(32MB) | oseq(32MB) | wts(28MB) = 124MB.
// d_out (64MB) doubles as two 32MB bf16 scratch halves until the final GEMM.
// ---------------------------------------------------------------------------

#define TOKENS 16384
#define DMODEL 1024

typedef unsigned short ushort_t;
typedef __attribute__((ext_vector_type(8))) short short8;
typedef __attribute__((ext_vector_type(4))) float floatx4;

__device__ __forceinline__ float b2f(ushort_t u) {
  union { uint32_t i; float f; } v; v.i = ((uint32_t)u) << 16; return v.f;
}
__device__ __forceinline__ ushort_t f2b(float f) {
  union { float f; uint32_t i; } v; v.f = f;
  uint32_t r = v.i + 0x7fffu + ((v.i >> 16) & 1u);
  return (ushort_t)(r >> 16);
}

// load 8 fp32 (16B-aligned), round to bf16, store 16B
__device__ __forceinline__ void pack8(const float* __restrict__ g, ushort_t* dst) {
  float4 x = *(const float4*)g;
  float4 y = *(const float4*)(g + 4);
  ushort_t o[8] = {f2b(x.x), f2b(x.y), f2b(x.z), f2b(x.w),
                   f2b(y.x), f2b(y.y), f2b(y.z), f2b(y.w)};
  *(uint4*)dst = *(uint4*)o;
}

// async global->LDS, 16B per lane (wave-uniform base + lane*16)
#define GLD16(g, l)                                                          \
  __builtin_amdgcn_global_load_lds(                                          \
      (const __attribute__((address_space(1))) void*)(g),                    \
      (__attribute__((address_space(3))) void*)(l), 16, 0, 0)

// ---------------------------------------------------------------------------
// weight pre-conversion: 14 matrices of 1024x1024 fp32 -> bf16
// ---------------------------------------------------------------------------
struct ConvArgs {
  const float* src[14];
  ushort_t* dst[14];
};

__global__ __launch_bounds__(256) void conv_w_kernel(ConvArgs a) {
  const int w = blockIdx.y;
  const int idx = (blockIdx.x * 256 + threadIdx.x) * 8;
  pack8(a.src[w] + idx, a.dst[w] + idx);
}

// generic fp32 -> bf16 conversion (output_seq)
__global__ __launch_bounds__(256) void conv_x_kernel(
    const float* __restrict__ src, ushort_t* __restrict__ dst) {
  const int idx = (blockIdx.x * 256 + threadIdx.x) * 8;
  pack8(src + idx, dst + idx);
}

// x = input + pe (fp32 in, bf16 out)
__global__ __launch_bounds__(256) void add_pe_kernel(
    const float* __restrict__ in, const float* __restrict__ pe,
    ushort_t* __restrict__ out) {
  int idx = (blockIdx.x * 256 + threadIdx.x) * 8;
  int d = idx & (DMODEL - 1);
  float4 a0 = *(const float4*)(in + idx);
  float4 a1 = *(const float4*)(in + idx + 4);
  float4 p0 = *(const float4*)(pe + d);
  float4 p1 = *(const float4*)(pe + d + 4);
  ushort_t o[8] = {f2b(a0.x + p0.x), f2b(a0.y + p0.y), f2b(a0.z + p0.z), f2b(a0.w + p0.w),
                   f2b(a1.x + p1.x), f2b(a1.y + p1.y), f2b(a1.z + p1.z), f2b(a1.w + p1.w)};
  *(uint4*)(out + idx) = *(uint4*)o;
}

// ---------------------------------------------------------------------------
// C[t,n] = sum_k A[t,k]*W[n,k] + bias[n].  M=16384, N=K=1024. All-bf16 A/W.
// 128x128 tile, 4 waves x (64x64), MFMA 16x16x32 bf16, BK=64 (16 K-iters).
// LDS swizzle: slot (row, j) holds global chunk (row, j^(row&7)) — permute
// the GLOBAL address per lane (GLD16's LDS side must stay lane-contiguous).
// Frag read chunk for (ks,quad) at row r: c=(ks*4+quad)^(r&7); r&7==lane&7
// -> conflict-free (2-way) ds_read_b128 at 128B row stride.
// ---------------------------------------------------------------------------
template <bool RELU, bool OUT32>
__global__ __launch_bounds__(256) void gemm_bt(
    const ushort_t* __restrict__ A, const ushort_t* __restrict__ W,
    const float* __restrict__ bias, void* __restrict__ Cp) {
  constexpr int K = 1024, N = 1024, BK = 64;
  __shared__ __align__(16) ushort_t smem[128 * 136];  // 34816B, epilogue union
  ushort_t* sA = smem;          // 128x64 bf16 = 16KB
  ushort_t* sB = smem + 8192;   // 128x64 bf16 = 16KB

  const int t = threadIdx.x;
  const int lane = t & 63;
  const int m0 = blockIdx.x * 128;
  const int n0 = blockIdx.y * 128;
  const int wm = ((t >> 6) >> 1) * 64;
  const int wn = ((t >> 6) & 1) * 64;

  floatx4 acc[4][4] = {};

  // staging: thread t -> LDS slot (row = s*32 + (t>>3), chunk j = t&7)
  // global source chunk = j ^ (row&7)  (row&7 == (t>>3)&7)
  const int rl = t >> 3;   // 0..31
  const int j8 = t & 7;
  const ushort_t* gA = A + (size_t)(m0 + rl) * K + ((j8 ^ (rl & 7)) * 8);
  const ushort_t* gW = W + (size_t)(n0 + rl) * K + ((j8 ^ (rl & 7)) * 8);
  const int lo = t * 8;

  for (int k0 = 0; k0 < K; k0 += BK) {
#pragma unroll
    for (int s = 0; s < 4; s++) {
      GLD16(gA + k0 + (size_t)(s * 32) * K, sA + s * 2048 + lo);
      GLD16(gW + k0 + (size_t)(s * 32) * K, sB + s * 2048 + lo);
    }
    __syncthreads();

#pragma unroll
    for (int ks = 0; ks < 2; ks++) {
      short8 af[4], bf[4];
#pragma unroll
      for (int i = 0; i < 4; i++) {
        const int cs = ((ks * 4 + (lane >> 4)) ^ (lane & 7)) * 8;
        af[i] = *(const short8*)&sA[(wm + i * 16 + (lane & 15)) * 64 + cs];
        bf[i] = *(const short8*)&sB[(wn + i * 16 + (lane & 15)) * 64 + cs];
      }
#pragma unroll
      for (int i = 0; i < 4; i++)
#pragma unroll
        for (int jj = 0; jj < 4; jj++)
          acc[i][jj] = __builtin_amdgcn_mfma_f32_16x16x32_bf16(af[i], bf[jj], acc[i][jj], 0, 0, 0);
    }
    __syncthreads();
  }

  // ---- epilogue. C/D layout: col=lane&15, row=(lane>>4)*4+reg [m89] ----
  const int rbase = (lane >> 4) * 4;

  if (OUT32) {
    // fp32 coalesced via LDS: two half-tiles of 64 rows x 132 fp32 (33792B)
    float* sCf = (float*)smem;
#pragma unroll
    for (int p = 0; p < 2; p++) {
      if (wm == p * 64) {
#pragma unroll
        for (int j = 0; j < 4; j++) {
          const int cl = wn + j * 16 + (lane & 15);
          const float bv = bias[n0 + cl];
#pragma unroll
          for (int i = 0; i < 4; i++)
#pragma unroll
            for (int r = 0; r < 4; r++) {
              float v = acc[i][j][r] + bv;
              if (RELU) v = fmaxf(v, 0.0f);
              sCf[(i * 16 + rbase + r) * 132 + cl] = v;
            }
        }
      }
      __syncthreads();
#pragma unroll
      for (int u = 0; u < 8; u++) {
        const int lin = u * 256 + t;        // 0..2047
        const int row = lin >> 5;           // 0..63
        const int cc = (lin & 31) * 4;      // 0..124
        float4 v = *(const float4*)&sCf[row * 132 + cc];
        *(float4*)((float*)Cp + (size_t)(m0 + p * 64 + row) * N + n0 + cc) = v;
      }
      __syncthreads();
    }
    return;
  }

  // bf16 path: acc -> sC (padded 136) -> coalesced row-major uint4 stores
  ushort_t* sC = smem;
#pragma unroll
  for (int j = 0; j < 4; j++) {
    const int cl = wn + j * 16 + (lane & 15);
    const float bv = bias[n0 + cl];
#pragma unroll
    for (int i = 0; i < 4; i++) {
      const int rl2 = wm + i * 16 + rbase;
#pragma unroll
      for (int r = 0; r < 4; r++) {
        float v = acc[i][j][r] + bv;
        if (RELU) v = fmaxf(v, 0.0f);
        sC[(rl2 + r) * 136 + cl] = f2b(v);
      }
    }
  }
  __syncthreads();
#pragma unroll
  for (int p = 0; p < 8; p++) {
    const int rl2 = p * 16 + (t >> 4);
    const int cl = (t & 15) * 8;
    uint4 v = *(const uint4*)&sC[rl2 * 136 + cl];
    *(uint4*)((ushort_t*)Cp + (size_t)(m0 + rl2) * N + n0 + cl) = v;
  }
}

// ---------------------------------------------------------------------------
// Per-token head-mix attention (bf16). One wave/token, 4 tokens/block.
// O may alias Q: all reads staged to LDS before any global write.
// ---------------------------------------------------------------------------
__global__ __launch_bounds__(256) void attn_kernel(
    const ushort_t* Q, const ushort_t* Kp, const ushort_t* Vp, ushort_t* O) {
  __shared__ __align__(16) ushort_t sq[4][1024];
  __shared__ __align__(16) ushort_t sk[4][1024];
  __shared__ __align__(16) ushort_t sv[4][1024];
  __shared__ float sp[4][64];

  const int t = threadIdx.x;
  const int w = t >> 6;
  const int lane = t & 63;
  const size_t base = ((size_t)blockIdx.x * 4 + w) * 1024;

  ((uint4*)sq[w])[lane] = ((const uint4*)(Q + base))[lane];
  ((uint4*)sq[w])[lane + 64] = ((const uint4*)(Q + base))[lane + 64];
  ((uint4*)sk[w])[lane] = ((const uint4*)(Kp + base))[lane];
  ((uint4*)sk[w])[lane + 64] = ((const uint4*)(Kp + base))[lane + 64];
  ((uint4*)sv[w])[lane] = ((const uint4*)(Vp + base))[lane];
  ((uint4*)sv[w])[lane + 64] = ((const uint4*)(Vp + base))[lane + 64];
  __syncthreads();

  {  // scores + softmax: lane = i*8 + j
    const int i = lane >> 3, j = lane & 7;
    const ushort_t* qr = &sq[w][i * 128];
    const ushort_t* kr = &sk[w][j * 128];
    float s = 0.0f;
#pragma unroll 16
    for (int h = 0; h < 128; h++) s += b2f(qr[h]) * b2f(kr[h]);
    s *= 0.08838834764831845f;  // 1/sqrt(128)
    float m = s;
#pragma unroll
    for (int off = 1; off < 8; off <<= 1) m = fmaxf(m, __shfl_xor(m, off, 64));
    float e = __expf(s - m);
    float sum = e;
#pragma unroll
    for (int off = 1; off < 8; off <<= 1) sum += __shfl_xor(sum, off, 64);
    sp[w][lane] = e / sum;
  }
  __syncthreads();

  {  // out[i][h] = sum_j P[i][j]*v[j][h]
    const int i = lane >> 3;
    const int hb = (lane & 7) * 16;
    float p[8];
#pragma unroll
    for (int jj = 0; jj < 8; jj++) p[jj] = sp[w][i * 8 + jj];
    float o[16];
#pragma unroll
    for (int h = 0; h < 16; h++) {
      float acc = 0.0f;
#pragma unroll
      for (int jj = 0; jj < 8; jj++) acc += p[jj] * b2f(sv[w][jj * 128 + hb + h]);
      o[h] = acc;
    }
    uint32_t packed[8];
#pragma unroll
    for (int u = 0; u < 8; u++)
      packed[u] = (uint32_t)f2b(o[2 * u]) | ((uint32_t)f2b(o[2 * u + 1]) << 16);
    uint4* dst = (uint4*)(O + base + i * 128 + hb);
    dst[0] = *(uint4*)&packed[0];
    dst[1] = *(uint4*)&packed[4];
  }
}

// ---------------------------------------------------------------------------
extern "C" void kernel_launch(void* const* d_in, const int* in_sizes, int n_in,
                              void* d_out, int out_size, void* d_ws, size_t ws_size,
                              hipStream_t stream) {
  const float* input_seq = (const float*)d_in[0];
  const float* output_seq = (const float*)d_in[1];
  const float* pe = (const float*)d_in[2];
  const float* wsrc[14] = {
      (const float*)d_in[3],  (const float*)d_in[5],  (const float*)d_in[7],
      (const float*)d_in[9],  (const float*)d_in[11], (const float*)d_in[13],
      (const float*)d_in[15], (const float*)d_in[17], (const float*)d_in[19],
      (const float*)d_in[21], (const float*)d_in[23], (const float*)d_in[25],
      (const float*)d_in[27], (const float*)d_in[29]};
  const float* enc_bq = (const float*)d_in[4];
  const float* enc_bk = (const float*)d_in[6];
  const float* enc_bv = (const float*)d_in[8];
  const float* enc_b1 = (const float*)d_in[10];
  const float* enc_b2 = (const float*)d_in[12];
  const float* dsq_b = (const float*)d_in[14];
  const float* dsk_b = (const float*)d_in[16];
  const float* dsv_b = (const float*)d_in[18];
  const float* dcq_b = (const float*)d_in[20];
  const float* dck_b = (const float*)d_in[22];
  const float* dcv_b = (const float*)d_in[24];
  const float* dec_b1 = (const float*)d_in[26];
  const float* dec_b2 = (const float*)d_in[28];
  const float* fc_b = (const float*)d_in[30];

  const size_t SZ = (size_t)TOKENS * DMODEL;   // 16.7M elems
  const size_t WSZ = (size_t)DMODEL * DMODEL;  // 1M elems
  ushort_t* bA = (ushort_t*)d_ws;        // 32MB
  ushort_t* bB = bA + SZ;                // 32MB
  ushort_t* oseq = bB + SZ;              // 32MB (output_seq in bf16)
  ushort_t* wts = oseq + SZ;             // 28MB bf16 weights
  ushort_t* oL = (ushort_t*)d_out;       // d_out lower 32MB as bf16 scratch
  ushort_t* oH = oL + SZ;                // d_out upper 32MB as bf16 scratch
  float* outf = (float*)d_out;

  // weight idx: 0 ewq,1 ewk,2 ewv,3 ew1,4 ew2,5 dsq,6 dsk,7 dsv,8 dcq,9 dck,
  //             10 dcv,11 dw1,12 dw2,13 fc
  ConvArgs ca;
#pragma unroll
  for (int i = 0; i < 14; i++) { ca.src[i] = wsrc[i]; ca.dst[i] = wts + (size_t)i * WSZ; }

  const dim3 gG(TOKENS / 128, DMODEL / 128);  // (128, 8)
  const dim3 blk(256);
  const int gPE = TOKENS * DMODEL / (256 * 8);  // 8192
  const int gAT = TOKENS / 4;                   // 4096

  conv_w_kernel<<<dim3(WSZ / (256 * 8), 14), blk, 0, stream>>>(ca);
  conv_x_kernel<<<gPE, blk, 0, stream>>>(output_seq, oseq);
  add_pe_kernel<<<gPE, blk, 0, stream>>>(input_seq, pe, bA);                   // bA = x
  // encoder self-attn
  gemm_bt<false, false><<<gG, blk, 0, stream>>>(bA, wts + 0 * WSZ, enc_bq, bB);  // bB = q
  gemm_bt<false, false><<<gG, blk, 0, stream>>>(bA, wts + 1 * WSZ, enc_bk, oL);  // oL = k
  gemm_bt<false, false><<<gG, blk, 0, stream>>>(bA, wts + 2 * WSZ, enc_bv, oH);  // oH = v
  attn_kernel<<<gAT, blk, 0, stream>>>(bB, oL, oH, bB);                          // bB = a
  // encoder FFN
  gemm_bt<true, false><<<gG, blk, 0, stream>>>(bB, wts + 3 * WSZ, enc_b1, bA);   // bA = h1
  gemm_bt<false, false><<<gG, blk, 0, stream>>>(bA, wts + 4 * WSZ, enc_b2, bB);  // bB = enc_out
  // decoder self-attn
  gemm_bt<false, false><<<gG, blk, 0, stream>>>(oseq, wts + 5 * WSZ, dsq_b, bA); // bA = q2
  gemm_bt<false, false><<<gG, blk, 0, stream>>>(oseq, wts + 6 * WSZ, dsk_b, oL); // oL = k2
  gemm_bt<false, false><<<gG, blk, 0, stream>>>(oseq, wts + 7 * WSZ, dsv_b, oH); // oH = v2
  attn_kernel<<<gAT, blk, 0, stream>>>(bA, oL, oH, bA);                          // bA = sa
  // decoder cross-attn (q from sa, k/v from enc_out)
  gemm_bt<false, false><<<gG, blk, 0, stream>>>(bA, wts + 8 * WSZ, dcq_b, oL);   // oL = q3
  gemm_bt<false, false><<<gG, blk, 0, stream>>>(bB, wts + 9 * WSZ, dck_b, oH);   // oH = k3
  gemm_bt<false, false><<<gG, blk, 0, stream>>>(bB, wts + 10 * WSZ, dcv_b, bA);  // bA = v3
  attn_kernel<<<gAT, blk, 0, stream>>>(oL, oH, bA, oL);                          // oL = ca
  // decoder FFN + final fc
  gemm_bt<true, false><<<gG, blk, 0, stream>>>(oL, wts + 11 * WSZ, dec_b1, bB);  // bB = h2
  gemm_bt<false, false><<<gG, blk, 0, stream>>>(bB, wts + 12 * WSZ, dec_b2, bA); // bA = dec_out
  gemm_bt<false, true><<<gG, blk, 0, stream>>>(bA, wts + 13 * WSZ, fc_b, outf);  // d_out fp32
}